// Round 4
// baseline (253.096 us; speedup 1.0000x reference)
//
#include <hip/hip_runtime.h>
#include <hip/hip_bf16.h>

// B=8, N=4096 (=64x64 spatial), C=768.
// Y = ReFFT2_spatial(X) @ (proj_w @ Wv)^T + proj_b,  Wv = qkv_w[1536:2304].
// K0 prep: twiddle fragment tables + Pb (bf16 proj_w) + Qb (bf16 Wv^T)
// K2: pass A twiddle-MFMA -> Ar'/Ai' in k2-MAJOR layout [b][k2 0..32][n1][c]
// K3: by<6 = M = Pb @ Qb^T; else FFT pass B (1 k2/block, contiguous staging)
// K4: Y = Xf @ M^T + b   (32x32x16 MFMA, BK=64, XOR-swizzled staging)

typedef __bf16 bf16x8 __attribute__((ext_vector_type(8)));
typedef __bf16 bf16x4 __attribute__((ext_vector_type(4)));
typedef float f32x4 __attribute__((ext_vector_type(4)));
typedef float f32x16 __attribute__((ext_vector_type(16)));
typedef unsigned short ushort_t;
typedef unsigned int uint_t;

typedef __attribute__((address_space(3))) unsigned int lds_u32;
typedef __attribute__((address_space(1))) unsigned int glob_u32;

__device__ __forceinline__ void gl_lds16(const void* g, void* l) {
  __builtin_amdgcn_global_load_lds((const glob_u32*)g, (lds_u32*)l, 16, 0, 0);
}

__device__ __forceinline__ ushort_t f2bf(float f) {
  union { __hip_bfloat16 h; ushort_t s; } cv;
  cv.h = __float2bfloat16(f);
  return cv.s;
}

// Swizzled fragment read: row-major [row][dword d] with d stored at d^sel2.
__device__ __forceinline__ bf16x8 ld_swz(const ushort_t* rowp, int D0, int sel2) {
  union { bf16x8 v; bf16x4 h[2]; } r;
  r.h[0] = *(const bf16x4*)(rowp + 2 * (D0 ^ sel2));
  r.h[1] = *(const bf16x4*)(rowp + 2 * ((D0 + 2) ^ sel2));
  return r.v;
}

// ---------- K0: twiddle tables + bf16 weight prep ----------
__global__ __launch_bounds__(256) void prep(const float* __restrict__ P,
                                            const float* __restrict__ Q,
                                            ushort_t* __restrict__ TwA,
                                            ushort_t* __restrict__ TwB,
                                            ushort_t* __restrict__ Pb,
                                            ushort_t* __restrict__ Qb) {
  __shared__ ushort_t Ts[4608];                  // 64x72 transpose tile
  const int t = threadIdx.x;
  if (blockIdx.x < 7) {                          // ---- twiddle tables ----
    const int id = blockIdx.x * 256 + t;         // 0..1791
    int m, k0, sn;
    ushort_t* out;
    if (id < 768) {
      int r = id % 384, cs = id / 384;
      int l = r & 63, ks = (r >> 6) & 1, mt = r >> 7;
      m = mt * 16 + (l & 15);
      k0 = ks * 32 + (l >> 4) * 8;
      sn = cs;
      out = TwA + id * 8;
    } else {
      int j = id - 768;
      int r = j % 512, cs = j / 512;
      int l = r & 63, ks = (r >> 6) & 1, mt = (r >> 7) & 1, wm = r >> 8;
      m = wm * 32 + mt * 16 + (l & 15);
      k0 = ks * 32 + (l >> 4) * 8;
      sn = cs;
      out = TwB + j * 8;
    }
#pragma unroll
    for (int e = 0; e < 8; ++e) {
      int ph = (m * (k0 + e)) & 63;
      float a = (float)ph * 0.09817477042468104f;  // 2*pi/64
      out[e] = f2bf(sn ? __sinf(a) : __cosf(a));
    }
  } else if (blockIdx.x < 151) {                 // ---- Qb transpose (144 tiles) ----
    const int tile = blockIdx.x - 7;
    const int ti = tile / 12, tj = tile % 12;
    const int r0 = t >> 4, c4 = (t & 15) * 4;
#pragma unroll
    for (int rr = 0; rr < 4; ++rr) {
      const int k = ti * 64 + r0 + rr * 16;
      f32x4 v = *(const f32x4*)&Q[(size_t)(1536 + k) * 768 + tj * 64 + c4];
#pragma unroll
      for (int j = 0; j < 4; ++j)
        Ts[(c4 + j) * 72 + r0 + rr * 16] = f2bf(v[j]);
    }
    __syncthreads();
    const int co = t >> 2, kq = (t & 3) * 16;
    uint4 v0 = *(const uint4*)&Ts[co * 72 + kq];
    uint4 v1 = *(const uint4*)&Ts[co * 72 + kq + 8];
    ushort_t* dst = Qb + (size_t)(tj * 64 + co) * 768 + ti * 64 + kq;
    *(uint4*)&dst[0] = v0;
    *(uint4*)&dst[8] = v1;
  } else {                                       // ---- Pb convert (288 blocks) ----
    const int cid = blockIdx.x - 151;
    const size_t off = (size_t)cid * 2048 + t * 8;
    f32x4 f0 = *(const f32x4*)&P[off];
    f32x4 f1 = *(const f32x4*)&P[off + 4];
    union { ushort_t u[8]; uint4 v; } pk;
#pragma unroll
    for (int j = 0; j < 4; ++j) { pk.u[j] = f2bf(f0[j]); pk.u[4 + j] = f2bf(f1[j]); }
    *(uint4*)&Pb[off] = pk.v;
  }
}

// ---------- K2: FFT pass A. Output k2-major: Ar'[(b*33+k2)*64 + n1][c] ----------
__global__ __launch_bounds__(256) void fft_a_pre(const float* __restrict__ X,
                                                 __hip_bfloat16* __restrict__ Ar,
                                                 __hip_bfloat16* __restrict__ Ai,
                                                 const ushort_t* __restrict__ TwA) {
  __shared__ ushort_t smem[9728];     // 19456 B: Xs [128][68 swz]; Ep2 [2][33][136] overlays
  const int t = threadIdx.x;
  const int c0 = blockIdx.x * 128;
  const int w = t >> 6, l = t & 63;
  const int lm = l & 15, lq = l >> 4;
  const int s = blockIdx.y;           // b*64 + n1
  const int b = s >> 6, n1 = s & 63;
  const float* src = X + (size_t)s * 64 * 768 + c0;
  // twiddle fragments: 12 coalesced 16B loads (L2-resident)
  const bf16x8* twa = (const bf16x8*)TwA;
  bf16x8 afc[3][2], afs[3][2];
#pragma unroll
  for (int mt = 0; mt < 3; ++mt)
#pragma unroll
    for (int ks = 0; ks < 2; ++ks) {
      afc[mt][ks] = twa[mt * 128 + ks * 64 + l];
      afs[mt][ks] = twa[384 + mt * 128 + ks * 64 + l];
    }
  // X staging: 8 dwordx4 loads/thread, transpose pack, atom-swizzled LDS writes
#pragma unroll
  for (int it = 0; it < 4; ++it) {
    const int pr = it * 8 + (t >> 5);        // n2-pair dword 0..31
    const int c = (t & 31) * 4;
    const float* rp = src + (size_t)(2 * pr) * 768 + c;
    f32x4 f0 = *(const f32x4*)rp;
    f32x4 f1 = *(const f32x4*)(rp + 768);
#pragma unroll
    for (int j = 0; j < 4; ++j) {
      uint_t pk = (uint_t)f2bf(f0[j]) | ((uint_t)f2bf(f1[j]) << 16);
      const int row = c + j;
      const int d = pr ^ (((row >> 4) & 7) << 1);
      *(uint_t*)&smem[row * 68 + 2 * d] = pk;
    }
  }
  __syncthreads();
  f32x4 accr[3][2] = {}, acci[3][2] = {};
#pragma unroll
  for (int ks = 0; ks < 2; ++ks) {
    bf16x8 bf[2];
#pragma unroll
    for (int nt = 0; nt < 2; ++nt) {
      int c = w * 32 + nt * 16 + lm;
      int sel2 = ((c >> 4) & 7) << 1;
      bf[nt] = ld_swz(&smem[c * 68], ks * 16 + lq * 4, sel2);
    }
#pragma unroll
    for (int mt = 0; mt < 3; ++mt)
#pragma unroll
      for (int nt = 0; nt < 2; ++nt) {
        accr[mt][nt] = __builtin_amdgcn_mfma_f32_16x16x32_bf16(afc[mt][ks], bf[nt], accr[mt][nt], 0, 0, 0);
        acci[mt][nt] = __builtin_amdgcn_mfma_f32_16x16x32_bf16(afs[mt][ks], bf[nt], acci[mt][nt], 0, 0, 0);
      }
  }
  // Single merged epilogue: both re+im transposed through Ep2 [arr][33][136]
  __syncthreads();                    // Xs dead
#pragma unroll
  for (int arr = 0; arr < 2; ++arr)
#pragma unroll
    for (int mt = 0; mt < 3; ++mt)
#pragma unroll
      for (int nt = 0; nt < 2; ++nt)
#pragma unroll
        for (int r = 0; r < 4; ++r) {
          int row = mt * 16 + lq * 4 + r;
          if (row <= 32) {
            int col = w * 32 + nt * 16 + lm;
            float v = arr ? acci[mt][nt][r] : accr[mt][nt][r];
            smem[arr * 4488 + row * 136 + col] = f2bf(v);
          }
        }
  __syncthreads();
#pragma unroll
  for (int it = 0; it < 5; ++it) {
    int idx = it * 256 + t;           // 2 arr x 33 rows x 16 chunks = 1056
    if (idx < 1056) {
      int arr = idx >= 528 ? 1 : 0;
      int rem = idx - arr * 528;
      int row = rem >> 4, cq = (rem & 15) * 8;   // row = k2
      uint4 v = *(const uint4*)&smem[arr * 4488 + row * 136 + cq];
      __hip_bfloat16* dst = arr ? Ai : Ar;
      *(uint4*)&dst[((size_t)(b * 33 + row) * 64 + n1) * 768 + c0 + cq] = v;
    }
  }
}

// ---------- K3: by<6 = M gemm head; else FFT pass B (1 k2/block) ----------
__global__ __launch_bounds__(256) void fft_b_mfma(const __hip_bfloat16* __restrict__ Ar,
                                                  const __hip_bfloat16* __restrict__ Ai,
                                                  __hip_bfloat16* __restrict__ Xf,
                                                  const ushort_t* __restrict__ TwB,
                                                  const ushort_t* __restrict__ Pb,
                                                  const ushort_t* __restrict__ Qb,
                                                  __hip_bfloat16* __restrict__ Mb) {
  __shared__ ushort_t smem[17408];    // 34816B: Rs 8704 | Is 8704 ; Ep2 [2][64][136] overlays
  const int t = threadIdx.x;
  const int w = t >> 6, l = t & 63;

  if (blockIdx.y < 6) {               // ---------------- M = Pb @ Qb^T ----------------
    ushort_t* As = smem;
    ushort_t* Bs = smem + 8192;
    const int m0 = blockIdx.y * 128;
    const int n0 = blockIdx.x * 128;
    const int wm = w & 1, wn = w >> 1;
    f32x16 acc[2][2] = {};
    const int srow = l >> 3;
    const int schunk = (l & 7) ^ srow;
    const int lr = l & 31, lh = l >> 5;
    for (int kt = 0; kt < 12; ++kt) {
      const int k0 = kt * 64;
#pragma unroll
      for (int i = 0; i < 4; ++i) {
        const int rbase = w * 32 + i * 8;
        const int row = rbase + srow;
        gl_lds16(&Pb[(size_t)(m0 + row) * 768 + k0 + schunk * 8], &As[rbase * 64]);
        gl_lds16(&Qb[(size_t)(n0 + row) * 768 + k0 + schunk * 8], &Bs[rbase * 64]);
      }
      __syncthreads();
#pragma unroll
      for (int ks = 0; ks < 4; ++ks) {
        bf16x8 af[2], bfv[2];
#pragma unroll
        for (int mt = 0; mt < 2; ++mt) {
          int row = wm * 64 + mt * 32 + lr;
          int ch = (ks * 2 + lh) ^ (lr & 7);
          af[mt] = *(const bf16x8*)&As[row * 64 + ch * 8];
        }
#pragma unroll
        for (int nt = 0; nt < 2; ++nt) {
          int row = wn * 64 + nt * 32 + lr;
          int ch = (ks * 2 + lh) ^ (lr & 7);
          bfv[nt] = *(const bf16x8*)&Bs[row * 64 + ch * 8];
        }
#pragma unroll
        for (int mt = 0; mt < 2; ++mt)
#pragma unroll
          for (int nt = 0; nt < 2; ++nt)
            acc[mt][nt] = __builtin_amdgcn_mfma_f32_32x32x16_bf16(af[mt], bfv[nt], acc[mt][nt], 0, 0, 0);
      }
      __syncthreads();
    }
#pragma unroll
    for (int nt = 0; nt < 2; ++nt) {
      const int col = n0 + wn * 64 + nt * 32 + lr;
#pragma unroll
      for (int mt = 0; mt < 2; ++mt) {
        const int rb = m0 + wm * 64 + mt * 32 + 4 * lh;
#pragma unroll
        for (int reg = 0; reg < 16; ++reg) {
          const int row = rb + (reg & 3) + 8 * (reg >> 2);
          Mb[(size_t)row * 768 + col] = __float2bfloat16(acc[mt][nt][reg]);
        }
      }
    }
    return;
  }

  // ---------------- FFT pass B ----------------
  ushort_t* Rs = smem;                // [c][d swz] stride 68
  ushort_t* Is = smem + 8704;
  const int bz = blockIdx.y - 6;      // b*33 + k2
  const int b = bz / 33, k2 = bz % 33;
  const int c0 = blockIdx.x * 128;
  // k2-major layout: contiguous 64 n1 rows (stride 1536 B) per (b,k2)
  const ushort_t* ar = (const ushort_t*)Ar + (size_t)(b * 33 + k2) * 64 * 768 + c0;
  const ushort_t* ai = (const ushort_t*)Ai + (size_t)(b * 33 + k2) * 64 * 768 + c0;
  const int wm = w & 1, wn = w >> 1;
  const int lm = l & 15, lq = l >> 4;
  const bf16x8* twb = (const bf16x8*)TwB;
  bf16x8 afc[2][2], afs[2][2];
#pragma unroll
  for (int mt = 0; mt < 2; ++mt)
#pragma unroll
    for (int ks = 0; ks < 2; ++ks) {
      afc[mt][ks] = twb[wm * 256 + mt * 128 + ks * 64 + l];
      afs[mt][ks] = twb[512 + wm * 256 + mt * 128 + ks * 64 + l];
    }
  // Ar/Ai staging: coalesced dwordx2 loads, register repack, swizzled LDS writes
#pragma unroll
  for (int it = 0; it < 4; ++it) {
    const int pr = it * 8 + (t >> 5);        // n1-pair dword 0..31
    const int c = (t & 31) * 4;
    const size_t o0 = (size_t)(2 * pr) * 768 + c;
    uint2 va = *(const uint2*)&ar[o0];
    uint2 vb = *(const uint2*)&ar[o0 + 768];
    uint2 ia = *(const uint2*)&ai[o0];
    uint2 ib = *(const uint2*)&ai[o0 + 768];
    uint_t rr[4], ss_[4];
    rr[0] = (va.x & 0xffffu) | (vb.x << 16);
    rr[1] = (va.x >> 16) | (vb.x & 0xffff0000u);
    rr[2] = (va.y & 0xffffu) | (vb.y << 16);
    rr[3] = (va.y >> 16) | (vb.y & 0xffff0000u);
    ss_[0] = (ia.x & 0xffffu) | (ib.x << 16);
    ss_[1] = (ia.x >> 16) | (ib.x & 0xffff0000u);
    ss_[2] = (ia.y & 0xffffu) | (ib.y << 16);
    ss_[3] = (ia.y >> 16) | (ib.y & 0xffff0000u);
#pragma unroll
    for (int j = 0; j < 4; ++j) {
      const int row = c + j;
      const int d = pr ^ (((row >> 4) & 7) << 1);
      *(uint_t*)&Rs[row * 68 + 2 * d] = rr[j];
      *(uint_t*)&Is[row * 68 + 2 * d] = ss_[j];
    }
  }
  __syncthreads();
  f32x4 accC[2][4] = {}, accS[2][4] = {};
#pragma unroll
  for (int ks = 0; ks < 2; ++ks) {
    bf16x8 bR[4], bI[4];
#pragma unroll
    for (int nt = 0; nt < 4; ++nt) {
      int c = wn * 64 + nt * 16 + lm;
      int sel2 = ((c >> 4) & 7) << 1;
      int D0 = ks * 16 + lq * 4;
      bR[nt] = ld_swz(&Rs[c * 68], D0, sel2);
      bI[nt] = ld_swz(&Is[c * 68], D0, sel2);
    }
#pragma unroll
    for (int mt = 0; mt < 2; ++mt)
#pragma unroll
      for (int nt = 0; nt < 4; ++nt) {
        accC[mt][nt] = __builtin_amdgcn_mfma_f32_16x16x32_bf16(afc[mt][ks], bR[nt], accC[mt][nt], 0, 0, 0);
        accS[mt][nt] = __builtin_amdgcn_mfma_f32_16x16x32_bf16(afs[mt][ks], bI[nt], accS[mt][nt], 0, 0, 0);
      }
  }
  const int nout = (k2 >= 1 && k2 <= 31) ? 2 : 1;
  __syncthreads();                    // Rs/Is dead from here; Ep2 overlays all 34816 B
  for (int o = 0; o < nout; ++o)
#pragma unroll
    for (int mt = 0; mt < 2; ++mt)
#pragma unroll
      for (int nt = 0; nt < 4; ++nt)
#pragma unroll
        for (int r = 0; r < 4; ++r) {
          int row = wm * 32 + mt * 16 + lq * 4 + r;   // k1
          int col = wn * 64 + nt * 16 + lm;           // c
          float v = o ? (accC[mt][nt][r] + accS[mt][nt][r])
                      : (accC[mt][nt][r] - accS[mt][nt][r]);
          smem[o * 8704 + row * 136 + col] = f2bf(v);
        }
  __syncthreads();
#pragma unroll
  for (int it = 0; it < 8; ++it) {
    int idx = it * 256 + t;
    if (idx < nout * 1024) {
      int o = idx >> 10, rem = idx & 1023;
      int k1 = rem >> 4, cq = (rem & 15) * 8;
      uint4 v = *(const uint4*)&smem[o * 8704 + k1 * 136 + cq];
      int k2o = o ? (64 - k2) : k2;
      *(uint4*)&Xf[((size_t)b * 4096 + k1 * 64 + k2o) * 768 + c0 + cq] = v;
    }
  }
}

// ---------- K4: Y[m,n] = sum_k Xf[m,k]*Mb[n,k] + bias[n] ----------
__global__ __launch_bounds__(256) void gemm_bt(const __hip_bfloat16* __restrict__ A,
                                               const __hip_bfloat16* __restrict__ B,
                                               const float* __restrict__ bias,
                                               float* __restrict__ C) {
  __shared__ ushort_t As[128 * 64];
  __shared__ ushort_t Bs[128 * 64];
  const int t = threadIdx.x, w = t >> 6, l = t & 63;
  const int L = blockIdx.x + blockIdx.y * 6;
  const int s = L >> 3, xcd = L & 7;
  const int n0 = (s % 6) * 128;
  const int m0 = ((s / 6) * 8 + xcd) * 128;
  const int wm = w & 1, wn = w >> 1;
  f32x16 acc[2][2] = {};
  const int srow = l >> 3;
  const int schunk = (l & 7) ^ srow;
  const int lr = l & 31, lh = l >> 5;
  for (int kt = 0; kt < 12; ++kt) {
    const int k0 = kt * 64;
#pragma unroll
    for (int i = 0; i < 4; ++i) {
      const int rbase = w * 32 + i * 8;
      const int row = rbase + srow;
      gl_lds16(&A[(size_t)(m0 + row) * 768 + k0 + schunk * 8], &As[rbase * 64]);
      gl_lds16(&B[(size_t)(n0 + row) * 768 + k0 + schunk * 8], &Bs[rbase * 64]);
    }
    __syncthreads();
#pragma unroll
    for (int ks = 0; ks < 4; ++ks) {
      bf16x8 af[2], bf[2];
#pragma unroll
      for (int mt = 0; mt < 2; ++mt) {
        int row = wm * 64 + mt * 32 + lr;
        int ch = (ks * 2 + lh) ^ (lr & 7);
        af[mt] = *(const bf16x8*)&As[row * 64 + ch * 8];
      }
#pragma unroll
      for (int nt = 0; nt < 2; ++nt) {
        int row = wn * 64 + nt * 32 + lr;
        int ch = (ks * 2 + lh) ^ (lr & 7);
        bf[nt] = *(const bf16x8*)&Bs[row * 64 + ch * 8];
      }
#pragma unroll
      for (int mt = 0; mt < 2; ++mt)
#pragma unroll
        for (int nt = 0; nt < 2; ++nt)
          acc[mt][nt] = __builtin_amdgcn_mfma_f32_32x32x16_bf16(af[mt], bf[nt], acc[mt][nt], 0, 0, 0);
    }
    __syncthreads();
  }
#pragma unroll
  for (int nt = 0; nt < 2; ++nt) {
    const int col = n0 + wn * 64 + nt * 32 + lr;
    const float bv = bias[col];
#pragma unroll
    for (int mt = 0; mt < 2; ++mt) {
      const int rb = m0 + wm * 64 + mt * 32 + 4 * lh;
#pragma unroll
      for (int reg = 0; reg < 16; ++reg) {
        const int row = rb + (reg & 3) + 8 * (reg >> 2);
        C[(size_t)row * 768 + col] = acc[mt][nt][reg] + bv;
      }
    }
  }
}

extern "C" void kernel_launch(void* const* d_in, const int* in_sizes, int n_in,
                              void* d_out, int out_size, void* d_ws, size_t ws_size,
                              hipStream_t stream) {
  const float* x      = (const float*)d_in[0];  // [8,4096,768]
  const float* qkv_w  = (const float*)d_in[1];  // [2304,768]
  const float* proj_w = (const float*)d_in[2];  // [768,768]
  const float* proj_b = (const float*)d_in[3];  // [768]
  float* out = (float*)d_out;                   // [8,4096,768] fp32

  char* ws = (char*)d_ws;
  const size_t MB_BYTES = (size_t)768 * 768 * 2;           // 1,179,648
  const size_t AK_BYTES = (size_t)8 * 33 * 64 * 768 * 2;   // 25,952,256 (k2-major A)
  const size_t XF_BYTES = (size_t)8 * 4096 * 768 * 2;      // 50,331,648
  __hip_bfloat16* Mb = (__hip_bfloat16*)ws;
  __hip_bfloat16* Ar = (__hip_bfloat16*)(ws + MB_BYTES);
  __hip_bfloat16* Ai = (__hip_bfloat16*)(ws + MB_BYTES + AK_BYTES);
  __hip_bfloat16* Xf = (__hip_bfloat16*)(ws + MB_BYTES + 2 * AK_BYTES);
  ushort_t* Pb  = (ushort_t*)(ws + MB_BYTES + 2 * AK_BYTES + XF_BYTES);
  ushort_t* Qb  = (ushort_t*)((char*)Pb + MB_BYTES);
  ushort_t* TwA = (ushort_t*)((char*)Qb + MB_BYTES);       // 12288 B
  ushort_t* TwB = (ushort_t*)((char*)TwA + 12288);         // 16384 B

  prep<<<dim3(439), 256, 0, stream>>>(proj_w, qkv_w, TwA, TwB, Pb, Qb);
  fft_a_pre<<<dim3(6, 512), 256, 0, stream>>>(x, Ar, Ai, TwA);
  fft_b_mfma<<<dim3(6, 270), 256, 0, stream>>>(Ar, Ai, Xf, TwB, Pb, Qb, Mb);
  gemm_bt<<<dim3(6, 256), 256, 0, stream>>>(Xf, Mb, proj_b, out);
}